// Round 2
// baseline (270.501 us; speedup 1.0000x reference)
//
#include <hip/hip_runtime.h>

#define EPSV 1e-5f

typedef short bf16x8 __attribute__((ext_vector_type(8)));
typedef float f32x4 __attribute__((ext_vector_type(4)));

static __device__ __forceinline__ unsigned short f2b(float f) {
  union { float f; unsigned u; } v; v.f = f;
  return (unsigned short)((v.u + 0x7fffu + ((v.u >> 16) & 1u)) >> 16);
}

// ---------- kernel 1: column stats of x (sum, sumsq per d) ----------
// grid (512) x 256 threads; thread owns 4 consecutive c via float4, 16 rows
__global__ void k_stats1(const float* __restrict__ x, float* __restrict__ xsum,
                         float* __restrict__ xsq) {
  const int c = threadIdx.x * 4;                         // 0..1020
  const int r0 = blockIdx.x * 16;
  float4 s = {0.f,0.f,0.f,0.f}, q = {0.f,0.f,0.f,0.f};
  float4 v[16];
#pragma unroll
  for (int r = 0; r < 16; ++r)
    v[r] = *(const float4*)(x + (size_t)(r0 + r) * 1024 + c);
#pragma unroll
  for (int r = 0; r < 16; ++r) {
    s.x += v[r].x; s.y += v[r].y; s.z += v[r].z; s.w += v[r].w;
    q.x = fmaf(v[r].x, v[r].x, q.x); q.y = fmaf(v[r].y, v[r].y, q.y);
    q.z = fmaf(v[r].z, v[r].z, q.z); q.w = fmaf(v[r].w, v[r].w, q.w);
  }
  atomicAdd(&xsum[c], s.x);   atomicAdd(&xsum[c+1], s.y);
  atomicAdd(&xsum[c+2], s.z); atomicAdd(&xsum[c+3], s.w);
  atomicAdd(&xsq[c], q.x);    atomicAdd(&xsq[c+1], q.y);
  atomicAdd(&xsq[c+2], q.z);  atomicAdd(&xsq[c+3], q.w);
}

// ---------- kernel 2: finalize BN1 -> packed params s1,t1 ----------
// pd layout per d (64 floats): [0:8)=s1, [8:16)=t1, [16:48)=W2*s2, [48:52)=t2c
__global__ void k_fin1(const float* __restrict__ W1, const float* __restrict__ g1,
                       const float* __restrict__ be1, const float* __restrict__ xsum,
                       const float* __restrict__ xsq, float* __restrict__ pd) {
  const int c = blockIdx.x * 256 + threadIdx.x;          // 0..8191
  const int d = c >> 3, i = c & 7;
  const float inv = 1.f / 8192.f;
  float mean = xsum[d] * inv;
  float var = xsq[d] * inv - mean * mean;
  float w = W1[c];
  float s1 = g1[c] * w * rsqrtf(w * w * var + EPSV);
  float t1 = be1[c] - s1 * mean;
  pd[d * 64 + i] = s1;
  pd[d * 64 + 8 + i] = t1;
}

// ---------- kernel 3: batch stats of dot (= h2pre - b2) per c2 ----------
__global__ __launch_bounds__(256) void k_stats2(const float* __restrict__ x,
    const float* __restrict__ pd, const float* __restrict__ W2,
    float* __restrict__ h2sum, float* __restrict__ h2sq) {
  __shared__ float red[8][32][8];
  const int t = threadIdx.x;
  const int dl = t & 31, slot = t >> 5;
  const int d = blockIdx.x * 32 + dl;
  const float4* pp = (const float4*)(pd + (size_t)d * 64);
  float s1v[8], t1v[8], w2v[32];
#pragma unroll
  for (int i = 0; i < 2; ++i) {
    float4 v = pp[i];
    s1v[i*4+0]=v.x; s1v[i*4+1]=v.y; s1v[i*4+2]=v.z; s1v[i*4+3]=v.w;
  }
#pragma unroll
  for (int i = 0; i < 2; ++i) {
    float4 v = pp[2+i];
    t1v[i*4+0]=v.x; t1v[i*4+1]=v.y; t1v[i*4+2]=v.z; t1v[i*4+3]=v.w;
  }
  const float4* wp = (const float4*)(W2 + (size_t)d * 32);
#pragma unroll
  for (int i = 0; i < 8; ++i) {
    float4 v = wp[i];
    w2v[i*4+0]=v.x; w2v[i*4+1]=v.y; w2v[i*4+2]=v.z; w2v[i*4+3]=v.w;
  }
  float s[4] = {0.f,0.f,0.f,0.f}, q[4] = {0.f,0.f,0.f,0.f};
  const int b0 = blockIdx.y * 256 + slot * 32;
  for (int r = 0; r < 32; r += 8) {
    float xv[8];
#pragma unroll
    for (int j = 0; j < 8; ++j)
      xv[j] = x[(size_t)(b0 + r + j) * 1024 + d];
#pragma unroll
    for (int j = 0; j < 8; ++j) {
      float a1[8];
#pragma unroll
      for (int i = 0; i < 8; ++i) a1[i] = fmaxf(fmaf(s1v[i], xv[j], t1v[i]), 0.f);
#pragma unroll
      for (int o = 0; o < 4; ++o) {
        float h = 0.f;
#pragma unroll
        for (int i = 0; i < 8; ++i) h = fmaf(a1[i], w2v[o*8+i], h);
        s[o] += h;
        q[o] = fmaf(h, h, q[o]);
      }
    }
  }
#pragma unroll
  for (int j = 0; j < 4; ++j) {
    red[slot][dl][j] = s[j];
    red[slot][dl][4+j] = q[j];
  }
  __syncthreads();
  // 256 threads reduce 256 (d_local, stat) slots across the 8 b-slots
  const int d2l = t >> 3, j = t & 7;
  float v = 0.f;
#pragma unroll
  for (int p = 0; p < 8; ++p) v += red[p][d2l][j];
  const int c2 = (blockIdx.x * 32 + d2l) * 4 + (t & 3);
  if (j < 4) atomicAdd(&h2sum[c2], v);
  else       atomicAdd(&h2sq[c2], v);
}

// ---------- kernel 4: finalize BN2 -> W2s, t2c into pd ----------
__global__ void k_fin2(const float* __restrict__ W2, const float* __restrict__ g2,
                       const float* __restrict__ be2, const float* __restrict__ h2sum,
                       const float* __restrict__ h2sq, float* __restrict__ pd) {
  const int c2 = blockIdx.x * 256 + threadIdx.x;         // 0..4095
  const int d = c2 >> 2, o = c2 & 3;
  const float inv = 1.f / 8192.f;
  float m = h2sum[c2] * inv;
  float var = h2sq[c2] * inv - m * m;
  float s2 = g2[c2] * rsqrtf(var + EPSV);
  float t2 = be2[c2] - s2 * m;
  pd[d * 64 + 48 + o] = t2;
#pragma unroll
  for (int i = 0; i < 8; ++i)
    pd[d * 64 + 16 + o * 8 + i] = W2[(size_t)d * 32 + o * 8 + i] * s2;
}

// ---------- kernel 5: Wfc fp32 -> bf16 (layout kept: [j][c2]) ----------
__global__ void k_wfc(const float* __restrict__ wfc, unsigned short* __restrict__ wb) {
  const int i = (blockIdx.x * 256 + threadIdx.x) * 4;
  float4 v = *(const float4*)(wfc + i);
  ushort4 o;
  o.x = f2b(v.x); o.y = f2b(v.y); o.z = f2b(v.z); o.w = f2b(v.w);
  *(ushort4*)(wb + i) = o;
}

// ---------- kernel 6: fused A-gen + GEMM ----------
// BM=64, BN=256 (all N), BK=128 c2 (=32 d), K-split=4 (blockIdx.y)
// grid (128, 4) x 256 threads (4 waves) -> 512 blocks = 2 blocks/CU
// wave w owns n-range [w*64, w*64+64)
__global__ __launch_bounds__(256, 2) void k_gemm(const float* __restrict__ x,
    const float* __restrict__ pd, const unsigned short* __restrict__ wb,
    const float* __restrict__ bfc, float* __restrict__ out) {
  __shared__ __align__(16) unsigned short As[64 * 136];  // pad 128->136
  const int t = threadIdx.x;
  const int lane = t & 63;
  const int wv = t >> 6;
  const int m0 = blockIdx.x * 64;
  const int dks = blockIdx.y * 256;                      // 256 d per K-split
  const int quad = lane >> 4;
  const int l15 = lane & 15;
  const int dl = t & 31, bs = t >> 5;
  // desync co-resident blocks' VALU/MFMA phases (sum order is irrelevant)
  const int chrot = (blockIdx.x & 1) << 2;

  f32x4 acc[4][4];
#pragma unroll
  for (int mt = 0; mt < 4; ++mt)
#pragma unroll
    for (int nt = 0; nt < 4; ++nt) {
      f32x4 z = {0.f, 0.f, 0.f, 0.f};
      acc[mt][nt] = z;
    }

  for (int chi = 0; chi < 8; ++chi) {
    const int ch = (chi + chrot) & 7;
    const int d = dks + ch * 32 + dl;
    const float4* pp = (const float4*)(pd + (size_t)d * 64);
    float pv[52];
#pragma unroll
    for (int i = 0; i < 13; ++i) {
      float4 v = pp[i];
      pv[i*4+0]=v.x; pv[i*4+1]=v.y; pv[i*4+2]=v.z; pv[i*4+3]=v.w;
    }
    __syncthreads();   // previous MFMA phase done reading As
    // ---- A-gen: recompute a2 tile (64 b x 32 d x 4 o2) in bf16 ----
#pragma unroll
    for (int r = 0; r < 8; ++r) {
      const int bl = bs * 8 + r;
      float xv = x[(size_t)(m0 + bl) * 1024 + d];
      float a1[8];
#pragma unroll
      for (int i = 0; i < 8; ++i) a1[i] = fmaxf(fmaf(pv[i], xv, pv[8+i]), 0.f);
      unsigned short o4[4];
#pragma unroll
      for (int o = 0; o < 4; ++o) {
        float h = pv[48 + o];
#pragma unroll
        for (int i = 0; i < 8; ++i) h = fmaf(a1[i], pv[16 + o*8 + i], h);
        o4[o] = f2b(fmaxf(h, 0.f));
      }
      *(ushort4*)&As[bl * 136 + dl * 4] = make_ushort4(o4[0], o4[1], o4[2], o4[3]);
    }
    __syncthreads();
    // ---- MFMA phase ----
    const size_t kb = (size_t)(dks + ch * 32) * 4;       // global c2 base
#pragma unroll
    for (int kk = 0; kk < 4; ++kk) {
      bf16x8 af[4];
#pragma unroll
      for (int mt = 0; mt < 4; ++mt)
        af[mt] = *(const bf16x8*)&As[(mt*16 + l15) * 136 + kk*32 + quad*8];
#pragma unroll
      for (int nt = 0; nt < 4; ++nt) {
        const int n = wv * 64 + nt * 16 + l15;
        bf16x8 bfr = *(const bf16x8*)&wb[(size_t)n * 4096 + kb + kk*32 + quad*8];
#pragma unroll
        for (int mt = 0; mt < 4; ++mt)
          acc[mt][nt] = __builtin_amdgcn_mfma_f32_16x16x32_bf16(af[mt], bfr,
                                                                acc[mt][nt], 0, 0, 0);
      }
    }
  }
  // ---- epilogue: fp32 atomic merge of the 4 K-splits; split 0 adds bias ----
#pragma unroll
  for (int nt = 0; nt < 4; ++nt) {
    const int col = wv * 64 + nt * 16 + l15;
    const float bias = (blockIdx.y == 0) ? bfc[col] : 0.f;
#pragma unroll
    for (int mt = 0; mt < 4; ++mt) {
#pragma unroll
      for (int r = 0; r < 4; ++r) {
        const int row = m0 + mt * 16 + quad * 4 + r;
        atomicAdd(&out[(size_t)row * 256 + col], acc[mt][nt][r] + bias);
      }
    }
  }
}

extern "C" void kernel_launch(void* const* d_in, const int* in_sizes, int n_in,
                              void* d_out, int out_size, void* d_ws, size_t ws_size,
                              hipStream_t stream) {
  const float* x   = (const float*)d_in[0];
  const float* W1  = (const float*)d_in[1];
  // d_in[2] = b1 (cancels in BN1), d_in[6] = b2 (cancels in BN2)
  const float* g1  = (const float*)d_in[3];
  const float* be1 = (const float*)d_in[4];
  const float* W2  = (const float*)d_in[5];
  const float* g2  = (const float*)d_in[7];
  const float* be2 = (const float*)d_in[8];
  const float* Wfc = (const float*)d_in[9];
  const float* bfc = (const float*)d_in[10];
  float* out = (float*)d_out;

  char* ws = (char*)d_ws;
  unsigned short* wb = (unsigned short*)ws;                 // 2 MB  bf16 Wfc
  float* pd    = (float*)(ws + (2u << 20));                 // 256 KB packed params
  float* stats = (float*)(ws + (2u << 20) + (256u << 10));  // 40 KB accumulators
  float* xsum   = stats;
  float* xsq    = stats + 1024;
  float* h2sum  = stats + 2048;
  float* h2sq   = stats + 2048 + 4096;

  hipMemsetAsync(stats, 0, (size_t)(1024*2 + 4096*2) * sizeof(float), stream);
  hipMemsetAsync(d_out, 0, (size_t)out_size * sizeof(float), stream);

  k_wfc   <<<dim3(1024),     256, 0, stream>>>(Wfc, wb);
  k_stats1<<<dim3(512),      256, 0, stream>>>(x, xsum, xsq);
  k_fin1  <<<dim3(32),       256, 0, stream>>>(W1, g1, be1, xsum, xsq, pd);
  k_stats2<<<dim3(32, 32),   256, 0, stream>>>(x, pd, W2, h2sum, h2sq);
  k_fin2  <<<dim3(16),       256, 0, stream>>>(W2, g2, be2, h2sum, h2sq, pd);
  k_gemm  <<<dim3(128, 4),   256, 0, stream>>>(x, pd, wb, bfc, out);
}

// Round 3
// 236.150 us; speedup vs baseline: 1.1455x; 1.1455x over previous
//
#include <hip/hip_runtime.h>

#define EPSV 1e-5f

typedef short bf16x8 __attribute__((ext_vector_type(8)));
typedef float f32x4 __attribute__((ext_vector_type(4)));

static __device__ __forceinline__ unsigned short f2b(float f) {
  union { float f; unsigned u; } v; v.f = f;
  return (unsigned short)((v.u + 0x7fffu + ((v.u >> 16) & 1u)) >> 16);
}

// ---------- kernel 1: column partial stats of x ----------
// grid 128; block handles 64 rows, thread owns 4 cols. No atomics:
// ps1[blk][0:1024)=sum, [1024:2048)=sumsq
__global__ void k_stats1(const float* __restrict__ x, float* __restrict__ ps1) {
  const int c = threadIdx.x * 4;
  const int r0 = blockIdx.x * 64;
  float4 s = {0.f,0.f,0.f,0.f}, q = {0.f,0.f,0.f,0.f};
  for (int g = 0; g < 8; ++g) {
    float4 v[8];
#pragma unroll
    for (int j = 0; j < 8; ++j)
      v[j] = *(const float4*)(x + (size_t)(r0 + g*8 + j) * 1024 + c);
#pragma unroll
    for (int j = 0; j < 8; ++j) {
      s.x += v[j].x; s.y += v[j].y; s.z += v[j].z; s.w += v[j].w;
      q.x = fmaf(v[j].x, v[j].x, q.x); q.y = fmaf(v[j].y, v[j].y, q.y);
      q.z = fmaf(v[j].z, v[j].z, q.z); q.w = fmaf(v[j].w, v[j].w, q.w);
    }
  }
  *(float4*)(ps1 + (size_t)blockIdx.x * 2048 + c) = s;
  *(float4*)(ps1 + (size_t)blockIdx.x * 2048 + 1024 + c) = q;
}

// ---------- kernel 1b: reduce 128 partials -> xsum/xsq ----------
__global__ void k_red1(const float* __restrict__ ps1, float* __restrict__ xstats) {
  const int j = blockIdx.x * 256 + threadIdx.x;          // 0..2047
  float v = 0.f;
  for (int b = 0; b < 128; b += 8) {
#pragma unroll
    for (int u = 0; u < 8; ++u) v += ps1[(size_t)(b + u) * 2048 + j];
  }
  xstats[j] = v;   // [0:1024)=sum, [1024:2048)=sumsq
}

// ---------- kernel 2: finalize BN1 -> pt rows 0..15 ----------
// pt layout [param i][d]: rows 0..7=s1_i, 8..15=t1_i, 16..47=W2s(o*8+i), 48..51=t2c
__global__ void k_fin1(const float* __restrict__ W1, const float* __restrict__ g1,
                       const float* __restrict__ be1, const float* __restrict__ xstats,
                       float* __restrict__ pt) {
  const int c = blockIdx.x * 256 + threadIdx.x;          // 0..8191
  const int d = c >> 3, i = c & 7;
  const float inv = 1.f / 8192.f;
  float mean = xstats[d] * inv;
  float var = xstats[1024 + d] * inv - mean * mean;
  float w = W1[c];
  float s1 = g1[c] * w * rsqrtf(w * w * var + EPSV);
  float t1 = be1[c] - s1 * mean;
  pt[i * 1024 + d] = s1;
  pt[(8 + i) * 1024 + d] = t1;
}

// ---------- kernel 3: batch partial stats of dot per c2 (no atomics) ----------
__global__ __launch_bounds__(256) void k_stats2(const float* __restrict__ x,
    const float* __restrict__ pt, const float* __restrict__ W2,
    float* __restrict__ ps2s, float* __restrict__ ps2q) {
  __shared__ float red[8][32][8];
  const int t = threadIdx.x;
  const int dl = t & 31, slot = t >> 5;
  const int d = blockIdx.x * 32 + dl;
  float s1v[8], t1v[8], w2v[32];
#pragma unroll
  for (int i = 0; i < 8; ++i) s1v[i] = pt[i * 1024 + d];
#pragma unroll
  for (int i = 0; i < 8; ++i) t1v[i] = pt[(8 + i) * 1024 + d];
  const float4* wp = (const float4*)(W2 + (size_t)d * 32);
#pragma unroll
  for (int i = 0; i < 8; ++i) {
    float4 v = wp[i];
    w2v[i*4+0]=v.x; w2v[i*4+1]=v.y; w2v[i*4+2]=v.z; w2v[i*4+3]=v.w;
  }
  float s[4] = {0.f,0.f,0.f,0.f}, q[4] = {0.f,0.f,0.f,0.f};
  const int b0 = blockIdx.y * 256 + slot * 32;
  for (int r = 0; r < 32; r += 8) {
    float xv[8];
#pragma unroll
    for (int j = 0; j < 8; ++j)
      xv[j] = x[(size_t)(b0 + r + j) * 1024 + d];
#pragma unroll
    for (int j = 0; j < 8; ++j) {
      float a1[8];
#pragma unroll
      for (int i = 0; i < 8; ++i) a1[i] = fmaxf(fmaf(s1v[i], xv[j], t1v[i]), 0.f);
#pragma unroll
      for (int o = 0; o < 4; ++o) {
        float h = 0.f;
#pragma unroll
        for (int i = 0; i < 8; ++i) h = fmaf(a1[i], w2v[o*8+i], h);
        s[o] += h;
        q[o] = fmaf(h, h, q[o]);
      }
    }
  }
#pragma unroll
  for (int j = 0; j < 4; ++j) {
    red[slot][dl][j] = s[j];
    red[slot][dl][4+j] = q[j];
  }
  __syncthreads();
  const int d2l = t >> 3, j = t & 7;
  float v = 0.f;
#pragma unroll
  for (int p = 0; p < 8; ++p) v += red[p][d2l][j];
  const int c2 = (blockIdx.x * 32 + d2l) * 4 + (t & 3);
  if (j < 4) ps2s[(size_t)blockIdx.y * 4096 + c2] = v;
  else       ps2q[(size_t)blockIdx.y * 4096 + c2] = v;
}

// ---------- kernel 4: reduce + finalize BN2 -> pt rows 16..51 ----------
__global__ void k_fin2(const float* __restrict__ W2, const float* __restrict__ g2,
                       const float* __restrict__ be2, const float* __restrict__ ps2s,
                       const float* __restrict__ ps2q, float* __restrict__ pt) {
  const int c2 = blockIdx.x * 256 + threadIdx.x;         // 0..4095
  const int d = c2 >> 2, o = c2 & 3;
  float sm = 0.f, sq = 0.f;
#pragma unroll
  for (int b = 0; b < 32; ++b) {
    sm += ps2s[(size_t)b * 4096 + c2];
    sq += ps2q[(size_t)b * 4096 + c2];
  }
  const float inv = 1.f / 8192.f;
  float m = sm * inv;
  float var = sq * inv - m * m;
  float s2 = g2[c2] * rsqrtf(var + EPSV);
  float t2 = be2[c2] - s2 * m;
  pt[(48 + o) * 1024 + d] = t2;
#pragma unroll
  for (int i = 0; i < 8; ++i)
    pt[(16 + o * 8 + i) * 1024 + d] = W2[(size_t)d * 32 + o * 8 + i] * s2;
}

// ---------- kernel 5: Wfc fp32 -> bf16, pre-swizzled fragment layout ----------
// frag id = k32b*16 + nb; lane(quad,l15): n=nb*16+l15, k=k32b*32+quad*8
// wb[(frag*64 + lane)*8 + j] = bf16(Wfc[n][k+j]) -> B loads fully coalesced
__global__ void k_wfc(const float* __restrict__ wfc, unsigned short* __restrict__ wb) {
  const int f = blockIdx.x * 256 + threadIdx.x;          // 0..131071
  const int l15 = f & 15, quad = (f >> 4) & 3, nb = (f >> 6) & 15, k32b = f >> 10;
  const int n = nb * 16 + l15;
  const int k = k32b * 32 + quad * 8;
  const float4* src = (const float4*)(wfc + (size_t)n * 4096 + k);
  float4 a = src[0], b = src[1];
  ushort4 o0, o1;
  o0.x = f2b(a.x); o0.y = f2b(a.y); o0.z = f2b(a.z); o0.w = f2b(a.w);
  o1.x = f2b(b.x); o1.y = f2b(b.y); o1.z = f2b(b.z); o1.w = f2b(b.w);
  *(ushort4*)(wb + (size_t)f * 8) = o0;
  *(ushort4*)(wb + (size_t)f * 8 + 4) = o1;
}

// ---------- kernel 6: fused A-gen + GEMM ----------
// BM=64, BN=256, chunk=32 d (128 c2), K-split=2; grid (128,2) x 256 threads
__global__ __launch_bounds__(256) void k_gemm(const float* __restrict__ x,
    const float* __restrict__ pt, const unsigned short* __restrict__ wb,
    const float* __restrict__ bfc, float* __restrict__ out) {
  // row stride 146 shorts = 73 dwords (73 mod 32 = 9): b128 reads 2-way (free)
  __shared__ __align__(16) unsigned short As[64 * 146];
  const int t = threadIdx.x;
  const int lane = t & 63;
  const int wv = t >> 6;
  const int m0 = blockIdx.x * 64;
  const int kHalf = blockIdx.y;
  const int d0 = kHalf * 512;
  const int quad = lane >> 4;
  const int l15 = lane & 15;
  const int dl = t & 31, bs = t >> 5;
  const int chrot = (blockIdx.x & 1) << 3;

  f32x4 acc[4][4];
#pragma unroll
  for (int mt = 0; mt < 4; ++mt)
#pragma unroll
    for (int nt = 0; nt < 4; ++nt) {
      f32x4 z = {0.f, 0.f, 0.f, 0.f};
      acc[mt][nt] = z;
    }

  for (int chi = 0; chi < 16; ++chi) {
    const int ch = (chi + chrot) & 15;
    const int d = d0 + ch * 32 + dl;
    // coalesced broadcast param loads: each is one 128B line for the wave
    float pv[52];
#pragma unroll
    for (int i = 0; i < 52; ++i) pv[i] = pt[i * 1024 + d];
    __syncthreads();   // previous MFMA phase done reading As
    // ---- A-gen: 64 b x 32 d x 4 o2 tile in bf16 ----
#pragma unroll
    for (int r = 0; r < 8; ++r) {
      const int bl = bs * 8 + r;
      float xv = x[(size_t)(m0 + bl) * 1024 + d];
      float a1[8];
#pragma unroll
      for (int i = 0; i < 8; ++i) a1[i] = fmaxf(fmaf(pv[i], xv, pv[8+i]), 0.f);
      unsigned short o4[4];
#pragma unroll
      for (int o = 0; o < 4; ++o) {
        float h = pv[48 + o];
#pragma unroll
        for (int i = 0; i < 8; ++i) h = fmaf(a1[i], pv[16 + o*8 + i], h);
        o4[o] = f2b(fmaxf(h, 0.f));
      }
      *(ushort4*)&As[bl * 146 + dl * 4] = make_ushort4(o4[0], o4[1], o4[2], o4[3]);
    }
    __syncthreads();
    // ---- MFMA phase; B loads are contiguous 1KB wave-loads ----
#pragma unroll
    for (int kk = 0; kk < 4; ++kk) {
      bf16x8 af[4];
#pragma unroll
      for (int mt = 0; mt < 4; ++mt)
        af[mt] = *(const bf16x8*)&As[(mt*16 + l15) * 146 + kk*32 + quad*8];
      const int k32b = kHalf * 64 + ch * 4 + kk;
#pragma unroll
      for (int nt = 0; nt < 4; ++nt) {
        const int frag = k32b * 16 + wv * 4 + nt;
        bf16x8 bfr = *(const bf16x8*)&wb[((size_t)frag * 64 + lane) * 8];
#pragma unroll
        for (int mt = 0; mt < 4; ++mt)
          acc[mt][nt] = __builtin_amdgcn_mfma_f32_16x16x32_bf16(af[mt], bfr,
                                                                acc[mt][nt], 0, 0, 0);
      }
    }
  }
  // ---- epilogue: atomic merge of 2 K-splits; split 0 adds bias ----
#pragma unroll
  for (int nt = 0; nt < 4; ++nt) {
    const int col = wv * 64 + nt * 16 + l15;
    const float bias = (kHalf == 0) ? bfc[col] : 0.f;
#pragma unroll
    for (int mt = 0; mt < 4; ++mt) {
#pragma unroll
      for (int r = 0; r < 4; ++r) {
        const int row = m0 + mt * 16 + quad * 4 + r;
        atomicAdd(&out[(size_t)row * 256 + col], acc[mt][nt][r] + bias);
      }
    }
  }
}

extern "C" void kernel_launch(void* const* d_in, const int* in_sizes, int n_in,
                              void* d_out, int out_size, void* d_ws, size_t ws_size,
                              hipStream_t stream) {
  const float* x   = (const float*)d_in[0];
  const float* W1  = (const float*)d_in[1];
  // d_in[2]=b1, d_in[6]=b2 cancel inside the train-mode batchnorms
  const float* g1  = (const float*)d_in[3];
  const float* be1 = (const float*)d_in[4];
  const float* W2  = (const float*)d_in[5];
  const float* g2  = (const float*)d_in[7];
  const float* be2 = (const float*)d_in[8];
  const float* Wfc = (const float*)d_in[9];
  const float* bfc = (const float*)d_in[10];
  float* out = (float*)d_out;

  char* ws = (char*)d_ws;
  unsigned short* wb = (unsigned short*)ws;               // 2 MB swizzled bf16 Wfc
  float* pt     = (float*)(ws + (2u << 20));              // 256 KB [param][d]
  float* shared = (float*)(ws + (2u << 20) + (256u << 10)); // 1 MB reused partials
  float* ps1  = shared;                                   // 128 x 2048 (stats1)
  float* ps2s = shared;                                   // 32 x 4096 (stats2 sum)
  float* ps2q = shared + 32 * 4096;                       // 32 x 4096 (stats2 sq)
  float* xstats = (float*)(ws + (2u << 20) + (256u << 10) + (1u << 20)); // 8 KB

  hipMemsetAsync(d_out, 0, (size_t)out_size * sizeof(float), stream);

  k_wfc   <<<dim3(512),    256, 0, stream>>>(Wfc, wb);
  k_stats1<<<dim3(128),    256, 0, stream>>>(x, ps1);
  k_red1  <<<dim3(8),      256, 0, stream>>>(ps1, xstats);
  k_fin1  <<<dim3(32),     256, 0, stream>>>(W1, g1, be1, xstats, pt);
  k_stats2<<<dim3(32, 32), 256, 0, stream>>>(x, pt, W2, ps2s, ps2q);
  k_fin2  <<<dim3(16),     256, 0, stream>>>(W2, g2, be2, ps2s, ps2q, pt);
  k_gemm  <<<dim3(128, 2), 256, 0, stream>>>(x, pt, wb, bfc, out);
}

// Round 4
// 186.968 us; speedup vs baseline: 1.4468x; 1.2630x over previous
//
#include <hip/hip_runtime.h>

#define EPSV 1e-5f

typedef short bf16x8 __attribute__((ext_vector_type(8)));
typedef float f32x4 __attribute__((ext_vector_type(4)));

static __device__ __forceinline__ unsigned short f2b(float f) {
  union { float f; unsigned u; } v; v.f = f;
  return (unsigned short)((v.u + 0x7fffu + ((v.u >> 16) & 1u)) >> 16);
}

// ---------- kernel A: fused Wfc->bf16 swizzle (blocks 0..511) +
//                      x column partial stats (blocks 512..767) ----------
// wb frag layout: frag id = k32b*16 + nb; lane(quad,l15): n=nb*16+l15,
// k=k32b*32+quad*8; wb[(frag*64+lane)*8 + j] = bf16(Wfc[n][k+j])
// ps1[blk][0:1024)=colsum, [1024:2048)=colsumsq  (256 partial blocks)
__global__ void k_pre(const float* __restrict__ wfc, unsigned short* __restrict__ wb,
                      const float* __restrict__ x, float* __restrict__ ps1) {
  if (blockIdx.x < 512) {
    const int f = blockIdx.x * 256 + threadIdx.x;        // 0..131071
    const int l15 = f & 15, quad = (f >> 4) & 3, nb = (f >> 6) & 15, k32b = f >> 10;
    const int n = nb * 16 + l15;
    const int k = k32b * 32 + quad * 8;
    const float4* src = (const float4*)(wfc + (size_t)n * 4096 + k);
    float4 a = src[0], b = src[1];
    ushort4 o0, o1;
    o0.x = f2b(a.x); o0.y = f2b(a.y); o0.z = f2b(a.z); o0.w = f2b(a.w);
    o1.x = f2b(b.x); o1.y = f2b(b.y); o1.z = f2b(b.z); o1.w = f2b(b.w);
    *(ushort4*)(wb + (size_t)f * 8) = o0;
    *(ushort4*)(wb + (size_t)f * 8 + 4) = o1;
  } else {
    const int blk = blockIdx.x - 512;                    // 0..255
    const int c = threadIdx.x * 4;
    const int r0 = blk * 32;
    float4 s = {0.f,0.f,0.f,0.f}, q = {0.f,0.f,0.f,0.f};
    for (int g = 0; g < 4; ++g) {
      float4 v[8];
#pragma unroll
      for (int j = 0; j < 8; ++j)
        v[j] = *(const float4*)(x + (size_t)(r0 + g*8 + j) * 1024 + c);
#pragma unroll
      for (int j = 0; j < 8; ++j) {
        s.x += v[j].x; s.y += v[j].y; s.z += v[j].z; s.w += v[j].w;
        q.x = fmaf(v[j].x, v[j].x, q.x); q.y = fmaf(v[j].y, v[j].y, q.y);
        q.z = fmaf(v[j].z, v[j].z, q.z); q.w = fmaf(v[j].w, v[j].w, q.w);
      }
    }
    *(float4*)(ps1 + (size_t)blk * 2048 + c) = s;
    *(float4*)(ps1 + (size_t)blk * 2048 + 1024 + c) = q;
  }
}

// ---------- kernel B: reduce 256 partials + finalize BN1 -> pt rows 0..15 ----
// pt layout [param i][d]: rows 0..7=s1_i, 8..15=t1_i, 16..47=W2s(o*8+i), 48..51=t2c
__global__ __launch_bounds__(256) void k_fin1(const float* __restrict__ ps1,
    const float* __restrict__ W1, const float* __restrict__ g1,
    const float* __restrict__ be1, float* __restrict__ pt) {
  __shared__ float redS[8][32], redQ[8][32];
  const int t = threadIdx.x;
  const int d0 = blockIdx.x * 32;
  const int dl = t & 31, slot = t >> 5;
  float s = 0.f, q = 0.f;
  for (int u = 0; u < 32; u += 8) {
#pragma unroll
    for (int w = 0; w < 8; ++w) {
      const size_t base = (size_t)(slot * 32 + u + w) * 2048 + d0 + dl;
      s += ps1[base];
      q += ps1[base + 1024];
    }
  }
  redS[slot][dl] = s; redQ[slot][dl] = q;
  __syncthreads();
  const int dloc = t >> 3, i = t & 7;                    // 32 d x 8 i
  float xs = 0.f, xq = 0.f;
#pragma unroll
  for (int p = 0; p < 8; ++p) { xs += redS[p][dloc]; xq += redQ[p][dloc]; }
  const float inv = 1.f / 8192.f;
  const int d = d0 + dloc;
  const int c = d * 8 + i;
  float mean = xs * inv;
  float var = xq * inv - mean * mean;
  float w = W1[c];
  float s1 = g1[c] * w * rsqrtf(w * w * var + EPSV);
  float t1 = be1[c] - s1 * mean;
  pt[i * 1024 + d] = s1;
  pt[(8 + i) * 1024 + d] = t1;
}

// ---------- kernel C: batch partial stats of dot per c2 (no atomics) ----------
__global__ __launch_bounds__(256) void k_stats2(const float* __restrict__ x,
    const float* __restrict__ pt, const float* __restrict__ W2,
    float* __restrict__ ps2s, float* __restrict__ ps2q) {
  __shared__ float red[8][32][8];
  const int t = threadIdx.x;
  const int dl = t & 31, slot = t >> 5;
  const int d = blockIdx.x * 32 + dl;
  float s1v[8], t1v[8], w2v[32];
#pragma unroll
  for (int i = 0; i < 8; ++i) s1v[i] = pt[i * 1024 + d];
#pragma unroll
  for (int i = 0; i < 8; ++i) t1v[i] = pt[(8 + i) * 1024 + d];
  const float4* wp = (const float4*)(W2 + (size_t)d * 32);
#pragma unroll
  for (int i = 0; i < 8; ++i) {
    float4 v = wp[i];
    w2v[i*4+0]=v.x; w2v[i*4+1]=v.y; w2v[i*4+2]=v.z; w2v[i*4+3]=v.w;
  }
  float s[4] = {0.f,0.f,0.f,0.f}, q[4] = {0.f,0.f,0.f,0.f};
  const int b0 = blockIdx.y * 256 + slot * 32;
  for (int r = 0; r < 32; r += 8) {
    float xv[8];
#pragma unroll
    for (int j = 0; j < 8; ++j)
      xv[j] = x[(size_t)(b0 + r + j) * 1024 + d];
#pragma unroll
    for (int j = 0; j < 8; ++j) {
      float a1[8];
#pragma unroll
      for (int i = 0; i < 8; ++i) a1[i] = fmaxf(fmaf(s1v[i], xv[j], t1v[i]), 0.f);
#pragma unroll
      for (int o = 0; o < 4; ++o) {
        float h = 0.f;
#pragma unroll
        for (int i = 0; i < 8; ++i) h = fmaf(a1[i], w2v[o*8+i], h);
        s[o] += h;
        q[o] = fmaf(h, h, q[o]);
      }
    }
  }
#pragma unroll
  for (int j = 0; j < 4; ++j) {
    red[slot][dl][j] = s[j];
    red[slot][dl][4+j] = q[j];
  }
  __syncthreads();
  const int d2l = t >> 3, j = t & 7;
  float v = 0.f;
#pragma unroll
  for (int p = 0; p < 8; ++p) v += red[p][d2l][j];
  const int c2 = (blockIdx.x * 32 + d2l) * 4 + (t & 3);
  if (j < 4) ps2s[(size_t)blockIdx.y * 4096 + c2] = v;
  else       ps2q[(size_t)blockIdx.y * 4096 + c2] = v;
}

// ---------- kernel D: reduce + finalize BN2 -> pt rows 16..51 ----------
__global__ void k_fin2(const float* __restrict__ W2, const float* __restrict__ g2,
                       const float* __restrict__ be2, const float* __restrict__ ps2s,
                       const float* __restrict__ ps2q, float* __restrict__ pt) {
  const int c2 = blockIdx.x * 256 + threadIdx.x;         // 0..4095
  const int d = c2 >> 2, o = c2 & 3;
  float sm = 0.f, sq = 0.f;
#pragma unroll
  for (int b = 0; b < 32; ++b) {
    sm += ps2s[(size_t)b * 4096 + c2];
    sq += ps2q[(size_t)b * 4096 + c2];
  }
  const float inv = 1.f / 8192.f;
  float m = sm * inv;
  float var = sq * inv - m * m;
  float s2 = g2[c2] * rsqrtf(var + EPSV);
  float t2 = be2[c2] - s2 * m;
  pt[(48 + o) * 1024 + d] = t2;
#pragma unroll
  for (int i = 0; i < 8; ++i)
    pt[(16 + o * 8 + i) * 1024 + d] = W2[(size_t)d * 32 + o * 8 + i] * s2;
}

// ---------- kernel E: fused A-gen + GEMM ----------
// BM=64, BN=256, chunk=32 d (128 c2), K-split=4; grid (128,4) x 256 threads
// -> 512 blocks = 2 blocks/CU (launch_bounds min 2 waves/EU)
__global__ __launch_bounds__(256, 2) void k_gemm(const float* __restrict__ x,
    const float* __restrict__ pt, const unsigned short* __restrict__ wb,
    const float* __restrict__ bfc, float* __restrict__ out) {
  // stride 136 shorts = 68 dwords (== 4 mod 32): b128 reads tile banks perfectly
  __shared__ __align__(16) unsigned short As[64 * 136];
  const int t = threadIdx.x;
  const int lane = t & 63;
  const int wv = t >> 6;
  const int m0 = blockIdx.x * 64;
  const int kQ = blockIdx.y;
  const int d0 = kQ * 256;
  const int quad = lane >> 4;
  const int l15 = lane & 15;
  const int dl = t & 31, bs = t >> 5;
  const int chrot = (blockIdx.x & 1) << 2;

  f32x4 acc[4][4];
#pragma unroll
  for (int mt = 0; mt < 4; ++mt)
#pragma unroll
    for (int nt = 0; nt < 4; ++nt) {
      f32x4 z = {0.f, 0.f, 0.f, 0.f};
      acc[mt][nt] = z;
    }

  for (int chi = 0; chi < 8; ++chi) {
    const int ch = (chi + chrot) & 7;
    const int d = d0 + ch * 32 + dl;
    // coalesced wave loads: 32 consecutive d per param row
    float pv[52];
#pragma unroll
    for (int i = 0; i < 52; ++i) pv[i] = pt[i * 1024 + d];
    __syncthreads();   // previous MFMA phase done reading As
    // ---- A-gen: 64 b x 32 d x 4 o2 tile in bf16 ----
#pragma unroll
    for (int r = 0; r < 8; ++r) {
      const int bl = bs * 8 + r;
      float xv = x[(size_t)(m0 + bl) * 1024 + d];
      float a1[8];
#pragma unroll
      for (int i = 0; i < 8; ++i) a1[i] = fmaxf(fmaf(pv[i], xv, pv[8+i]), 0.f);
      unsigned short o4[4];
#pragma unroll
      for (int o = 0; o < 4; ++o) {
        float h = pv[48 + o];
#pragma unroll
        for (int i = 0; i < 8; ++i) h = fmaf(a1[i], pv[16 + o*8 + i], h);
        o4[o] = f2b(fmaxf(h, 0.f));
      }
      *(ushort4*)&As[bl * 136 + dl * 4] = make_ushort4(o4[0], o4[1], o4[2], o4[3]);
    }
    __syncthreads();
    // ---- MFMA phase; B loads are contiguous 1KB wave-loads ----
#pragma unroll
    for (int kk = 0; kk < 4; ++kk) {
      bf16x8 af[4];
#pragma unroll
      for (int mt = 0; mt < 4; ++mt)
        af[mt] = *(const bf16x8*)&As[(mt*16 + l15) * 136 + kk*32 + quad*8];
      const int k32b = kQ * 32 + ch * 4 + kk;
#pragma unroll
      for (int nt = 0; nt < 4; ++nt) {
        const int frag = k32b * 16 + wv * 4 + nt;
        bf16x8 bfr = *(const bf16x8*)&wb[((size_t)frag * 64 + lane) * 8];
#pragma unroll
        for (int mt = 0; mt < 4; ++mt)
          acc[mt][nt] = __builtin_amdgcn_mfma_f32_16x16x32_bf16(af[mt], bfr,
                                                                acc[mt][nt], 0, 0, 0);
      }
    }
  }
  // ---- epilogue: atomic merge of 4 K-splits; split 0 adds bias ----
#pragma unroll
  for (int nt = 0; nt < 4; ++nt) {
    const int col = wv * 64 + nt * 16 + l15;
    const float bias = (kQ == 0) ? bfc[col] : 0.f;
#pragma unroll
    for (int mt = 0; mt < 4; ++mt) {
#pragma unroll
      for (int r = 0; r < 4; ++r) {
        const int row = m0 + mt * 16 + quad * 4 + r;
        atomicAdd(&out[(size_t)row * 256 + col], acc[mt][nt][r] + bias);
      }
    }
  }
}

extern "C" void kernel_launch(void* const* d_in, const int* in_sizes, int n_in,
                              void* d_out, int out_size, void* d_ws, size_t ws_size,
                              hipStream_t stream) {
  const float* x   = (const float*)d_in[0];
  const float* W1  = (const float*)d_in[1];
  // d_in[2]=b1, d_in[6]=b2 cancel inside the train-mode batchnorms
  const float* g1  = (const float*)d_in[3];
  const float* be1 = (const float*)d_in[4];
  const float* W2  = (const float*)d_in[5];
  const float* g2  = (const float*)d_in[7];
  const float* be2 = (const float*)d_in[8];
  const float* Wfc = (const float*)d_in[9];
  const float* bfc = (const float*)d_in[10];
  float* out = (float*)d_out;

  char* ws = (char*)d_ws;
  unsigned short* wb = (unsigned short*)ws;                 // 2 MB swizzled bf16 Wfc
  float* pt     = (float*)(ws + (2u << 20));                // 256 KB [param][d]
  float* shared = (float*)(ws + (2u << 20) + (256u << 10)); // 2 MB reused partials
  float* ps1  = shared;                                     // 256 x 2048 (stats1)
  float* ps2s = shared;                                     // 32 x 4096 (stats2 sum)
  float* ps2q = shared + 32 * 4096;                         // 32 x 4096 (stats2 sq)

  hipMemsetAsync(d_out, 0, (size_t)out_size * sizeof(float), stream);

  k_pre   <<<dim3(768),    256, 0, stream>>>(Wfc, wb, x, ps1);
  k_fin1  <<<dim3(32),     256, 0, stream>>>(ps1, W1, g1, be1, pt);
  k_stats2<<<dim3(32, 32), 256, 0, stream>>>(x, pt, W2, ps2s, ps2q);
  k_fin2  <<<dim3(16),     256, 0, stream>>>(W2, g2, be2, ps2s, ps2q, pt);
  k_gemm  <<<dim3(128, 4), 256, 0, stream>>>(x, pt, wb, bfc, out);
}